// Round 1
// baseline (2567.184 us; speedup 1.0000x reference)
//
#include <hip/hip_runtime.h>
#include <hip/hip_bf16.h>

// Problem constants (from reference): B=128, T=512, D=1024, H=128, 4H=512.
#define BATCH 128
#define TSTEPS 512
#define HID 128
#define GATES 512   // 4*H
#define M_TOTAL (BATCH * TSTEPS)  // 65536

__device__ __forceinline__ float sigmoidf_fast(float x) {
    return 1.0f / (1.0f + __expf(-x));
}
__device__ __forceinline__ float tanhf_fast(float x) {
    return 1.0f - 2.0f / (__expf(2.0f * x) + 1.0f);
}

// ---------------------------------------------------------------------------
// GEMM: out[m][n] = sum_k A[m][k] * W[n][k] + b0[n] + b1[n]
// A: [M, K] row-major, W: [512, K] row-major, out: [M, 512].
// 128x128 tile, BK=16, 256 threads, 8x8 per thread.
// ---------------------------------------------------------------------------
template<int K>
__global__ __launch_bounds__(256) void gemm_bias_k(
    const float* __restrict__ A,
    const float* __restrict__ W,
    const float* __restrict__ b0,
    const float* __restrict__ b1,
    float* __restrict__ out)
{
    constexpr int BM = 128, BN = 128, BK = 16;
    __shared__ float As[BK][BM];
    __shared__ float Bs[BK][BN];

    const int tid = threadIdx.x;
    const int tx = tid & 15;        // n-direction, 8 cols each
    const int ty = tid >> 4;        // m-direction, 8 rows each
    const int m0 = blockIdx.x * BM;
    const int n0 = blockIdx.y * BN;

    // Tile-load assignment: 512 float4 per 128x16 tile, 2 per thread.
    const int f0 = tid, f1 = tid + 256;
    const int ar0 = f0 >> 2, ak0 = (f0 & 3) * 4;
    const int ar1 = f1 >> 2, ak1 = (f1 & 3) * 4;

    const float* pa0 = A + (size_t)(m0 + ar0) * K + ak0;
    const float* pa1 = A + (size_t)(m0 + ar1) * K + ak1;
    const float* pw0 = W + (size_t)(n0 + ar0) * K + ak0;
    const float* pw1 = W + (size_t)(n0 + ar1) * K + ak1;

    float bias8[8];
    #pragma unroll
    for (int j = 0; j < 8; ++j) {
        int n = n0 + tx * 8 + j;
        bias8[j] = b0[n] + b1[n];
    }
    float acc[8][8];
    #pragma unroll
    for (int i = 0; i < 8; ++i)
        #pragma unroll
        for (int j = 0; j < 8; ++j) acc[i][j] = bias8[j];

    for (int k0 = 0; k0 < K; k0 += BK) {
        const float4 a0 = *(const float4*)(pa0 + k0);
        const float4 a1 = *(const float4*)(pa1 + k0);
        const float4 w0 = *(const float4*)(pw0 + k0);
        const float4 w1 = *(const float4*)(pw1 + k0);
        __syncthreads();   // previous compute done before overwriting LDS
        As[ak0 + 0][ar0] = a0.x; As[ak0 + 1][ar0] = a0.y;
        As[ak0 + 2][ar0] = a0.z; As[ak0 + 3][ar0] = a0.w;
        As[ak1 + 0][ar1] = a1.x; As[ak1 + 1][ar1] = a1.y;
        As[ak1 + 2][ar1] = a1.z; As[ak1 + 3][ar1] = a1.w;
        Bs[ak0 + 0][ar0] = w0.x; Bs[ak0 + 1][ar0] = w0.y;
        Bs[ak0 + 2][ar0] = w0.z; Bs[ak0 + 3][ar0] = w0.w;
        Bs[ak1 + 0][ar1] = w1.x; Bs[ak1 + 1][ar1] = w1.y;
        Bs[ak1 + 2][ar1] = w1.z; Bs[ak1 + 3][ar1] = w1.w;
        __syncthreads();
        #pragma unroll
        for (int kk = 0; kk < BK; ++kk) {
            const float4 av0 = *(const float4*)&As[kk][ty * 8];
            const float4 av1 = *(const float4*)&As[kk][ty * 8 + 4];
            const float4 bv0 = *(const float4*)&Bs[kk][tx * 8];
            const float4 bv1 = *(const float4*)&Bs[kk][tx * 8 + 4];
            const float a[8]  = {av0.x, av0.y, av0.z, av0.w, av1.x, av1.y, av1.z, av1.w};
            const float bb[8] = {bv0.x, bv0.y, bv0.z, bv0.w, bv1.x, bv1.y, bv1.z, bv1.w};
            #pragma unroll
            for (int i = 0; i < 8; ++i)
                #pragma unroll
                for (int j = 0; j < 8; ++j)
                    acc[i][j] = __fmaf_rn(a[i], bb[j], acc[i][j]);
        }
    }

    #pragma unroll
    for (int i = 0; i < 8; ++i) {
        float* orow = out + (size_t)(m0 + ty * 8 + i) * GATES + n0 + tx * 8;
        *(float4*)orow       = make_float4(acc[i][0], acc[i][1], acc[i][2], acc[i][3]);
        *(float4*)(orow + 4) = make_float4(acc[i][4], acc[i][5], acc[i][6], acc[i][7]);
    }
}

// ---------------------------------------------------------------------------
// LSTM recurrence: one workgroup per batch element, 1024 threads.
// Thread (g = tid>>1, kh = tid&1) computes half the 128-length dot for gate g,
// pair-summed with __shfl_xor. w_hh row halves live in registers.
// Optionally writes full h sequence (layer 0) and/or fused FC logits (layer 1).
// ---------------------------------------------------------------------------
__global__ __launch_bounds__(1024) void lstm_rec(
    const float* __restrict__ xg,     // [B*T, 512] pre-activations (biases folded)
    const float* __restrict__ w_hh,   // [512, 128]
    float* __restrict__ h_all,        // [B*T, 128] or nullptr
    const float* __restrict__ fc_w,   // [8, 128] or nullptr
    const float* __restrict__ fc_b,   // [8]
    float* __restrict__ logits)       // [B, 8] or nullptr
{
    const int b   = blockIdx.x;
    const int tid = threadIdx.x;
    const int g   = tid >> 1;     // gate-output index 0..511
    const int kh  = tid & 1;      // which k-half of the dot

    __shared__ float h_s[HID];
    __shared__ float act_s[GATES];

    // w_hh[g][kh*64 .. kh*64+63] -> 16 float4 in registers
    float4 w[16];
    const float4* wrow = (const float4*)(w_hh + (size_t)g * HID + kh * 64);
    #pragma unroll
    for (int i = 0; i < 16; ++i) w[i] = wrow[i];

    if (tid < HID) h_s[tid] = 0.0f;
    float c = 0.0f;   // thread tid<128 owns cell state c[tid]
    __syncthreads();

    const float* xgb = xg + (size_t)b * TSTEPS * GATES;

    for (int t = 0; t < TSTEPS; ++t) {
        // issue the xg load early so it overlaps the dot
        float xv = 0.0f;
        if (kh == 0) xv = xgb[(size_t)t * GATES + g];

        const float4* hs4 = (const float4*)h_s + kh * 16;
        float p = 0.0f;
        #pragma unroll
        for (int i = 0; i < 16; ++i) {
            const float4 hv = hs4[i];
            p = __fmaf_rn(w[i].x, hv.x, p);
            p = __fmaf_rn(w[i].y, hv.y, p);
            p = __fmaf_rn(w[i].z, hv.z, p);
            p = __fmaf_rn(w[i].w, hv.w, p);
        }
        p += __shfl_xor(p, 1);

        if (kh == 0) {
            const float s = p + xv;
            const int gate = g >> 7;            // 0:i 1:f 2:g 3:o (wave-uniform)
            act_s[g] = (gate == 2) ? tanhf_fast(s) : sigmoidf_fast(s);
        }
        __syncthreads();

        if (tid < HID) {
            const float ig = act_s[tid];
            const float fg = act_s[tid + 128];
            const float gg = act_s[tid + 256];
            const float og = act_s[tid + 384];
            c = __fmaf_rn(fg, c, ig * gg);
            const float h = og * tanhf_fast(c);
            h_s[tid] = h;
            if (h_all) h_all[((size_t)b * TSTEPS + t) * HID + tid] = h;
        }
        __syncthreads();
    }

    // fused FC head (layer 1 only): logits[b][o] = h . fc_w[o] + fc_b[o]
    if (logits && tid < 8) {
        float s = fc_b[tid];
        const float* wr = fc_w + tid * HID;
        #pragma unroll 8
        for (int k = 0; k < HID; ++k) s = __fmaf_rn(wr[k], h_s[k], s);
        logits[b * 8 + tid] = s;
    }
}

// ---------------------------------------------------------------------------
extern "C" void kernel_launch(void* const* d_in, const int* in_sizes, int n_in,
                              void* d_out, int out_size, void* d_ws, size_t ws_size,
                              hipStream_t stream) {
    const float* x     = (const float*)d_in[0];
    const float* w_ih0 = (const float*)d_in[1];
    const float* w_hh0 = (const float*)d_in[2];
    const float* b_ih0 = (const float*)d_in[3];
    const float* b_hh0 = (const float*)d_in[4];
    const float* w_ih1 = (const float*)d_in[5];
    const float* w_hh1 = (const float*)d_in[6];
    const float* b_ih1 = (const float*)d_in[7];
    const float* b_hh1 = (const float*)d_in[8];
    const float* fc_w  = (const float*)d_in[9];
    const float* fc_b  = (const float*)d_in[10];
    float* out = (float*)d_out;

    float* xg = (float*)d_ws;                              // [65536, 512] f32 = 128 MB
    float* h1 = (float*)d_ws + (size_t)M_TOTAL * GATES;    // [65536, 128] f32 = 32 MB

    dim3 gg(M_TOTAL / 128, GATES / 128);  // (512, 4)
    dim3 gb(256);

    // layer 0: xg0 = x @ w_ih0^T + b_ih0 + b_hh0
    gemm_bias_k<1024><<<gg, gb, 0, stream>>>(x, w_ih0, b_ih0, b_hh0, xg);
    // layer 0 recurrence -> h1 (full sequence)
    lstm_rec<<<BATCH, 1024, 0, stream>>>(xg, w_hh0, h1, nullptr, nullptr, nullptr);
    // layer 1: xg1 = h1 @ w_ih1^T + b_ih1 + b_hh1
    gemm_bias_k<128><<<gg, gb, 0, stream>>>(h1, w_ih1, b_ih1, b_hh1, xg);
    // layer 1 recurrence + fused FC -> logits
    lstm_rec<<<BATCH, 1024, 0, stream>>>(xg, w_hh1, nullptr, fc_w, fc_b, out);
}

// Round 2
// 1747.730 us; speedup vs baseline: 1.4689x; 1.4689x over previous
//
#include <hip/hip_runtime.h>
#include <hip/hip_bf16.h>

// Problem constants: B=128, T=512, D=1024, H=128, 4H=512.
#define BATCH 128
#define TSTEPS 512
#define HID 128
#define GATES 512
#define M_TOTAL (BATCH * TSTEPS)  // 65536

typedef _Float16 h2_t __attribute__((ext_vector_type(2)));

__device__ __forceinline__ float sigmoidf_fast(float x) {
    return 1.0f / (1.0f + __expf(-x));
}
__device__ __forceinline__ float tanhf_fast(float x) {
    return 1.0f - 2.0f / (__expf(2.0f * x) + 1.0f);
}

__device__ __forceinline__ float fdot2h(h2_t a, h2_t b, float c) {
#if __has_builtin(__builtin_amdgcn_fdot2)
    return __builtin_amdgcn_fdot2(a, b, c, false);
#else
    return c + (float)a[0] * (float)b[0] + (float)a[1] * (float)b[1];
#endif
}

// ---------------------------------------------------------------------------
// GEMM: computes A[M,K] @ W[512,K]^T + b0 + b1, writes xg in TRANSPOSED-chunk
// layout xgT[b][t>>2][g][t&3] so the recurrence streams 4 steps per float4.
// 128x128 tile, BK=16, 256 threads, 8x8 per thread.
// Cols per thread: tx*4..+3 and 64+tx*4..+3 (16B-stride Bs reads = 2-way bank
// aliasing = free, vs 4-way at tx*8).
// ---------------------------------------------------------------------------
template<int K>
__global__ __launch_bounds__(256) void gemm_bias_k(
    const float* __restrict__ A,
    const float* __restrict__ W,
    const float* __restrict__ b0,
    const float* __restrict__ b1,
    float* __restrict__ xgT)
{
    constexpr int BM = 128, BN = 128, BK = 16;
    __shared__ float As[BK][BM];
    __shared__ float Bs[BK][BN];

    const int tid = threadIdx.x;
    const int tx = tid & 15;        // n-direction
    const int ty = tid >> 4;        // m-direction, 8 rows each
    const int n0 = blockIdx.x * BN; // grid.x = 4 n-blocks (adjacent dispatch shares A-tile in L2)
    const int m0 = blockIdx.y * BM;

    const int f0 = tid, f1 = tid + 256;
    const int ar0 = f0 >> 2, ak0 = (f0 & 3) * 4;
    const int ar1 = f1 >> 2, ak1 = (f1 & 3) * 4;

    const float* pa0 = A + (size_t)(m0 + ar0) * K + ak0;
    const float* pa1 = A + (size_t)(m0 + ar1) * K + ak1;
    const float* pw0 = W + (size_t)(n0 + ar0) * K + ak0;
    const float* pw1 = W + (size_t)(n0 + ar1) * K + ak1;

    float bias8[8];
    #pragma unroll
    for (int j = 0; j < 8; ++j) {
        int n = n0 + ((j < 4) ? (tx * 4 + j) : (64 + tx * 4 + j - 4));
        bias8[j] = b0[n] + b1[n];
    }
    float acc[8][8];
    #pragma unroll
    for (int i = 0; i < 8; ++i)
        #pragma unroll
        for (int j = 0; j < 8; ++j) acc[i][j] = bias8[j];

    for (int k0 = 0; k0 < K; k0 += BK) {
        const float4 a0 = *(const float4*)(pa0 + k0);
        const float4 a1 = *(const float4*)(pa1 + k0);
        const float4 w0 = *(const float4*)(pw0 + k0);
        const float4 w1 = *(const float4*)(pw1 + k0);
        __syncthreads();
        As[ak0 + 0][ar0] = a0.x; As[ak0 + 1][ar0] = a0.y;
        As[ak0 + 2][ar0] = a0.z; As[ak0 + 3][ar0] = a0.w;
        As[ak1 + 0][ar1] = a1.x; As[ak1 + 1][ar1] = a1.y;
        As[ak1 + 2][ar1] = a1.z; As[ak1 + 3][ar1] = a1.w;
        Bs[ak0 + 0][ar0] = w0.x; Bs[ak0 + 1][ar0] = w0.y;
        Bs[ak0 + 2][ar0] = w0.z; Bs[ak0 + 3][ar0] = w0.w;
        Bs[ak1 + 0][ar1] = w1.x; Bs[ak1 + 1][ar1] = w1.y;
        Bs[ak1 + 2][ar1] = w1.z; Bs[ak1 + 3][ar1] = w1.w;
        __syncthreads();
        #pragma unroll
        for (int kk = 0; kk < BK; ++kk) {
            const float4 av0 = *(const float4*)&As[kk][ty * 8];
            const float4 av1 = *(const float4*)&As[kk][ty * 8 + 4];
            const float4 bv0 = *(const float4*)&Bs[kk][tx * 4];
            const float4 bv1 = *(const float4*)&Bs[kk][64 + tx * 4];
            const float a[8]  = {av0.x, av0.y, av0.z, av0.w, av1.x, av1.y, av1.z, av1.w};
            const float bb[8] = {bv0.x, bv0.y, bv0.z, bv0.w, bv1.x, bv1.y, bv1.z, bv1.w};
            #pragma unroll
            for (int i = 0; i < 8; ++i)
                #pragma unroll
                for (int j = 0; j < 8; ++j)
                    acc[i][j] = __fmaf_rn(a[i], bb[j], acc[i][j]);
        }
    }

    // Epilogue: xgT[b][tc][n][tl], float4 packs 4 consecutive t per gate n.
    const int bi = m0 >> 9;
    const int t0 = (m0 & 511) + ty * 8;     // multiple of 8
    float4* xo = (float4*)xgT;              // float4 index = (bi*128 + tc)*512 + n
    #pragma unroll
    for (int j = 0; j < 8; ++j) {
        const int n = n0 + ((j < 4) ? (tx * 4 + j) : (64 + tx * 4 + j - 4));
        float4 v0 = make_float4(acc[0][j], acc[1][j], acc[2][j], acc[3][j]);
        float4 v1 = make_float4(acc[4][j], acc[5][j], acc[6][j], acc[7][j]);
        xo[(size_t)(bi * 128 + (t0 >> 2)) * 512 + n]     = v0;
        xo[(size_t)(bi * 128 + (t0 >> 2) + 1) * 512 + n] = v1;
    }
}

// ---------------------------------------------------------------------------
// Fused dual-layer recurrence. 256 blocks x 1024 threads.
// Blocks [0,128): layer-0 producer — reads xgT, ships h1 (half2) + flags.
// Blocks [128,256): layer-1 consumer — spins per-column flags, fuses the
// w_ih1 dot (so no separate K=128 GEMM) and the FC head.
// All dots are v_dot2_f32_f16; cell state c stays fp32.
// Producer never waits on consumer => deadlock-free without co-residency.
// ---------------------------------------------------------------------------
__global__ __launch_bounds__(1024, 4) void fused_rec(
    const float* __restrict__ xgT,
    const float* __restrict__ w_hh0,
    const float* __restrict__ w_ih1,
    const float* __restrict__ w_hh1,
    const float* __restrict__ b_ih1,
    const float* __restrict__ b_hh1,
    const float* __restrict__ fc_w,
    const float* __restrict__ fc_b,
    unsigned int* __restrict__ h1g,   // [128][512][64] half2-as-uint
    int* __restrict__ flags,          // [128][64]  (poisoned negative => consumer waits)
    float* __restrict__ logits)       // [128][8]
{
    const int blk = blockIdx.x;
    const int L1  = blk >= BATCH;
    const int b   = blk & (BATCH - 1);
    const int tid = threadIdx.x;
    const int g   = tid >> 1;
    const int kh  = tid & 1;

    __shared__ h2_t h2s[64];          // h_{t-1} in half2
    __shared__ float act_s[GATES];
    __shared__ h2_t hin2[8 * 64];     // consumer: 8-step chunk of layer-0 h

    h2_t whh[32], wih[32];
    {
        const float* wr = (L1 ? w_hh1 : w_hh0) + (size_t)g * HID + kh * 64;
        #pragma unroll
        for (int i = 0; i < 32; ++i)
            whh[i] = (h2_t){(_Float16)wr[2 * i], (_Float16)wr[2 * i + 1]};
    }
    float bias = 0.f;
    if (L1) {
        const float* wr = w_ih1 + (size_t)g * HID + kh * 64;
        #pragma unroll
        for (int i = 0; i < 32; ++i)
            wih[i] = (h2_t){(_Float16)wr[2 * i], (_Float16)wr[2 * i + 1]};
        if (kh == 0) bias = b_ih1[g] + b_hh1[g];
    }

    if (tid < 64) h2s[tid] = (h2_t){(_Float16)0.f, (_Float16)0.f};
    float c = 0.f;

    const float4* xgTb = (const float4*)xgT + (size_t)b * 128 * 512 + g;
    float4 cur4 = make_float4(0.f, 0.f, 0.f, 0.f);
    if (!L1 && kh == 0) cur4 = xgTb[0];

    unsigned int* h1row = h1g + (size_t)b * TSTEPS * 64;
    int* flagb = flags + b * 64;

    __syncthreads();

    float4 xv4 = cur4;
    for (int t8 = 0; t8 < 64; ++t8) {
        if (L1) {
            if (tid < 64) {
                // per-column release/acquire pairing: this thread acquires the
                // flag released by the producer thread that wrote column tid.
                while (__hip_atomic_load(&flagb[tid], __ATOMIC_ACQUIRE,
                                         __HIP_MEMORY_SCOPE_AGENT) < t8 + 1) {}
                #pragma unroll
                for (int r = 0; r < 8; ++r) {
                    union { unsigned int u; h2_t h; } cv;
                    cv.u = h1row[(size_t)(t8 * 8 + r) * 64 + tid];
                    hin2[r * 64 + tid] = cv.h;
                }
            }
            __syncthreads();
        }
        #pragma unroll
        for (int u = 0; u < 8; ++u) {
            const int t = t8 * 8 + u;
            if (u == 0 || u == 4) {
                xv4 = cur4;
                if (!L1 && kh == 0) {   // prefetch next 4 steps of xg (4-step lookahead)
                    int tc = (t >> 2) + 1; if (tc > 127) tc = 127;
                    cur4 = xgTb[(size_t)tc * 512];
                }
            }
            const float xv = ((u & 3) == 0) ? xv4.x : ((u & 3) == 1) ? xv4.y
                           : ((u & 3) == 2) ? xv4.z : xv4.w;

            float p0 = 0.f, p1 = 0.f;
            const h2_t* hb = h2s + kh * 32;
            #pragma unroll
            for (int i = 0; i < 32; i += 2) {
                p0 = fdot2h(whh[i],     hb[i],     p0);
                p1 = fdot2h(whh[i + 1], hb[i + 1], p1);
            }
            if (L1) {
                const h2_t* xb = hin2 + u * 64 + kh * 32;
                #pragma unroll
                for (int i = 0; i < 32; i += 2) {
                    p0 = fdot2h(wih[i],     xb[i],     p0);
                    p1 = fdot2h(wih[i + 1], xb[i + 1], p1);
                }
            }
            float p = p0 + p1;
            p += __shfl_xor(p, 1);
            if (kh == 0) {
                const float s = p + (L1 ? bias : xv);
                act_s[g] = (g >= 256 && g < 384) ? tanhf_fast(s) : sigmoidf_fast(s);
            }
            __syncthreads();
            if (tid < HID) {
                const float ig = act_s[tid];
                const float fg = act_s[tid + 128];
                const float gg = act_s[tid + 256];
                const float og = act_s[tid + 384];
                c = __fmaf_rn(fg, c, ig * gg);
                const float h = og * tanhf_fast(c);
                const float hn = __shfl_down(h, 1);
                if ((tid & 1) == 0) {
                    union { h2_t h; unsigned int u; } pk;
                    pk.h = (h2_t){(_Float16)h, (_Float16)hn};
                    h2s[tid >> 1] = pk.h;
                    if (!L1)
                        __hip_atomic_store(&h1row[(size_t)t * 64 + (tid >> 1)], pk.u,
                                           __ATOMIC_RELAXED, __HIP_MEMORY_SCOPE_AGENT);
                }
                if (L1 && t == TSTEPS - 1) act_s[tid] = h;  // stash fp32 h_T for FC
            }
            __syncthreads();
        }
        if (!L1 && tid < HID && (tid & 1) == 0)
            __hip_atomic_store(&flagb[tid >> 1], t8 + 1,
                               __ATOMIC_RELEASE, __HIP_MEMORY_SCOPE_AGENT);
    }

    if (L1 && tid < 8) {   // FC head on final h (fp32, from act_s stash)
        float s = fc_b[tid];
        const float* wr = fc_w + tid * HID;
        #pragma unroll 4
        for (int k = 0; k < HID; ++k) s = __fmaf_rn(wr[k], act_s[k], s);
        logits[b * 8 + tid] = s;
    }
}

// ---------------------------------------------------------------------------
extern "C" void kernel_launch(void* const* d_in, const int* in_sizes, int n_in,
                              void* d_out, int out_size, void* d_ws, size_t ws_size,
                              hipStream_t stream) {
    const float* x     = (const float*)d_in[0];
    const float* w_ih0 = (const float*)d_in[1];
    const float* w_hh0 = (const float*)d_in[2];
    const float* b_ih0 = (const float*)d_in[3];
    const float* b_hh0 = (const float*)d_in[4];
    const float* w_ih1 = (const float*)d_in[5];
    const float* w_hh1 = (const float*)d_in[6];
    const float* b_ih1 = (const float*)d_in[7];
    const float* b_hh1 = (const float*)d_in[8];
    const float* fc_w  = (const float*)d_in[9];
    const float* fc_b  = (const float*)d_in[10];
    float* out = (float*)d_out;

    // ws layout: xgT 128MB | h1g 16MB | flags 32KB   (total ~151 MB)
    float*        xgT   = (float*)d_ws;
    unsigned int* h1g   = (unsigned int*)((char*)d_ws + (size_t)M_TOTAL * GATES * 4);
    int*          flags = (int*)((char*)d_ws + (size_t)M_TOTAL * GATES * 4
                                             + (size_t)BATCH * TSTEPS * 64 * 4);

    dim3 gg(4, 512);   // x = n-block (4), y = m-block (512): A-tile reuse adjacency
    gemm_bias_k<1024><<<gg, dim3(256), 0, stream>>>(x, w_ih0, b_ih0, b_hh0, xgT);
    fused_rec<<<dim3(2 * BATCH), dim3(1024), 0, stream>>>(
        xgT, w_hh0, w_ih1, w_hh1, b_ih1, b_hh1, fc_w, fc_b, h1g, flags, out);
}

// Round 3
// 1500.935 us; speedup vs baseline: 1.7104x; 1.1644x over previous
//
#include <hip/hip_runtime.h>
#include <hip/hip_bf16.h>

// Problem constants: B=128, T=512, D=1024, H=128, 4H=512.
#define BATCH 128
#define TSTEPS 512
#define HID 128
#define GATES 512
#define M_TOTAL (BATCH * TSTEPS)  // 65536

typedef _Float16 h2_t  __attribute__((ext_vector_type(2)));
typedef _Float16 half4 __attribute__((ext_vector_type(4)));
typedef _Float16 half8 __attribute__((ext_vector_type(8)));
typedef float    f32x4 __attribute__((ext_vector_type(4)));

__device__ __forceinline__ float sigmoidf_fast(float x) {
    return 1.0f / (1.0f + __expf(-x));
}
__device__ __forceinline__ float tanhf_fast(float x) {
    return 1.0f - 2.0f / (__expf(2.0f * x) + 1.0f);
}
__device__ __forceinline__ float fdot2h(h2_t a, h2_t b, float c) {
#if __has_builtin(__builtin_amdgcn_fdot2)
    return __builtin_amdgcn_fdot2(a, b, c, false);
#else
    return c + (float)a[0] * (float)b[0] + (float)a[1] * (float)b[1];
#endif
}

// ---------------------------------------------------------------------------
// Preconvert W (512x1024 fp32) to f16 hi/lo split.
// ---------------------------------------------------------------------------
__global__ __launch_bounds__(256) void convert_w(
    const float* __restrict__ src, _Float16* __restrict__ hi, _Float16* __restrict__ lo)
{
    const int i = blockIdx.x * 256 + threadIdx.x;   // x4 elements, 131072 threads
    float4 v = ((const float4*)src)[i];
    half4 h, l;
    h[0] = (_Float16)v.x; l[0] = (_Float16)(v.x - (float)h[0]);
    h[1] = (_Float16)v.y; l[1] = (_Float16)(v.y - (float)h[1]);
    h[2] = (_Float16)v.z; l[2] = (_Float16)(v.z - (float)h[2]);
    h[3] = (_Float16)v.w; l[3] = (_Float16)(v.w - (float)h[3]);
    *(half4*)&hi[4 * i] = h;
    *(half4*)&lo[4 * i] = l;
}

// ---------------------------------------------------------------------------
// MFMA GEMM with fused f16 hi/lo split of A:
//   xg[m][n] = sum_k A[m][k]*W[n][k] + b0[n] + b1[n]
// via 3 products ah*wh + ah*wl + al*wh (dropped al*wl ~ 2^-22 relative).
// 128x128 tile, BK=32, 256 threads (4 waves, each a 4x4 grid of 16x16 tiles).
// LDS chunk layout q=(kb,m): elem (m, kb*8+j) at [(kb*128+m)*8+j] -> frag reads
// bank-uniform; staging ds_writes lane-consecutive (2-way = free).
// ---------------------------------------------------------------------------
__global__ __launch_bounds__(256, 2) void gemm_mfma(
    const float* __restrict__ A,        // [M][1024] fp32
    const _Float16* __restrict__ Wh,    // [512][1024]
    const _Float16* __restrict__ Wl,
    const float* __restrict__ b0,
    const float* __restrict__ b1,
    float* __restrict__ xg)             // [M][512]
{
    constexpr int K = 1024;
    __shared__ __align__(16) _Float16 sXh[128 * 32];
    __shared__ __align__(16) _Float16 sXl[128 * 32];
    __shared__ __align__(16) _Float16 sWh[128 * 32];
    __shared__ __align__(16) _Float16 sWl[128 * 32];

    const int tid = threadIdx.x;
    const int lane = tid & 63, wv = tid >> 6;
    const int wm = wv & 1, wn = wv >> 1;
    const int n0 = blockIdx.x * 128;   // n fastest: adjacent blocks share A rows
    const int m0 = blockIdx.y * 128;

    const int ar = tid & 127, aks = (tid >> 7) * 16;
    const float* pA = A + (size_t)(m0 + ar) * K + aks;
    const _Float16* pWh0 = Wh + (size_t)(n0 + (tid & 127)) * K + (tid >> 7) * 8;
    const _Float16* pWl0 = Wl + (size_t)(n0 + (tid & 127)) * K + (tid >> 7) * 8;

    f32x4 acc[4][4];
    #pragma unroll
    for (int nt = 0; nt < 4; ++nt) {
        const int cn = n0 + wn * 64 + nt * 16 + (lane & 15);
        const float bv = b0[cn] + b1[cn];
        #pragma unroll
        for (int mt = 0; mt < 4; ++mt) acc[mt][nt] = (f32x4){bv, bv, bv, bv};
    }

    float xv[16];
    half8 w0h, w1h, w0l, w1l;
    #pragma unroll
    for (int j = 0; j < 4; ++j) *(float4*)&xv[4 * j] = *(const float4*)(pA + 4 * j);
    w0h = *(const half8*)(pWh0);      w1h = *(const half8*)(pWh0 + 16);
    w0l = *(const half8*)(pWl0);      w1l = *(const half8*)(pWl0 + 16);

    const int kb0 = (tid >> 7) * 2;
    for (int ks = 0; ks < 32; ++ks) {
        half8 hh0, hh1, hl0, hl1;
        #pragma unroll
        for (int j = 0; j < 8; ++j) {
            _Float16 h = (_Float16)xv[j];
            hh0[j] = h; hl0[j] = (_Float16)(xv[j] - (float)h);
        }
        #pragma unroll
        for (int j = 0; j < 8; ++j) {
            _Float16 h = (_Float16)xv[8 + j];
            hh1[j] = h; hl1[j] = (_Float16)(xv[8 + j] - (float)h);
        }
        if (ks) __syncthreads();    // previous compute done before LDS overwrite
        *(half8*)&sXh[(size_t)((kb0    ) * 128 + ar) * 8] = hh0;
        *(half8*)&sXh[(size_t)((kb0 + 1) * 128 + ar) * 8] = hh1;
        *(half8*)&sXl[(size_t)((kb0    ) * 128 + ar) * 8] = hl0;
        *(half8*)&sXl[(size_t)((kb0 + 1) * 128 + ar) * 8] = hl1;
        *(half8*)&sWh[(size_t)tid * 8]         = w0h;
        *(half8*)&sWh[(size_t)(tid + 256) * 8] = w1h;
        *(half8*)&sWl[(size_t)tid * 8]         = w0l;
        *(half8*)&sWl[(size_t)(tid + 256) * 8] = w1l;
        __syncthreads();

        if (ks < 31) {              // prefetch next K-step during MFMA
            const int kn = (ks + 1) * 32;
            #pragma unroll
            for (int j = 0; j < 4; ++j)
                *(float4*)&xv[4 * j] = *(const float4*)(pA + kn + 4 * j);
            w0h = *(const half8*)(pWh0 + kn);      w1h = *(const half8*)(pWh0 + kn + 16);
            w0l = *(const half8*)(pWl0 + kn);      w1l = *(const half8*)(pWl0 + kn + 16);
        }

        const int fr = lane & 15, kb = lane >> 4;
        half8 ah[4], al[4], bh[4], bl[4];
        #pragma unroll
        for (int mt = 0; mt < 4; ++mt) {
            const int idx = (kb * 128 + wm * 64 + mt * 16 + fr) * 8;
            ah[mt] = *(const half8*)&sXh[idx];
            al[mt] = *(const half8*)&sXl[idx];
        }
        #pragma unroll
        for (int nt = 0; nt < 4; ++nt) {
            const int idx = (kb * 128 + wn * 64 + nt * 16 + fr) * 8;
            bh[nt] = *(const half8*)&sWh[idx];
            bl[nt] = *(const half8*)&sWl[idx];
        }
        #pragma unroll
        for (int mt = 0; mt < 4; ++mt)
            #pragma unroll
            for (int nt = 0; nt < 4; ++nt) {
                acc[mt][nt] = __builtin_amdgcn_mfma_f32_16x16x32_f16(ah[mt], bh[nt], acc[mt][nt], 0, 0, 0);
                acc[mt][nt] = __builtin_amdgcn_mfma_f32_16x16x32_f16(ah[mt], bl[nt], acc[mt][nt], 0, 0, 0);
                acc[mt][nt] = __builtin_amdgcn_mfma_f32_16x16x32_f16(al[mt], bh[nt], acc[mt][nt], 0, 0, 0);
            }
    }

    // epilogue: C/D layout col=lane&15, row=(lane>>4)*4+r
    #pragma unroll
    for (int mt = 0; mt < 4; ++mt) {
        const int rm = m0 + wm * 64 + mt * 16 + (lane >> 4) * 4;
        #pragma unroll
        for (int nt = 0; nt < 4; ++nt) {
            const int cn = n0 + wn * 64 + nt * 16 + (lane & 15);
            #pragma unroll
            for (int r = 0; r < 4; ++r)
                xg[(size_t)(rm + r) * GATES + cn] = acc[mt][nt][r];
        }
    }
}

// ---------------------------------------------------------------------------
// Fused dual-layer recurrence. 256 blocks x 512 threads (8 waves).
// Blocks [0,128): layer-0 producer; [128,256): layer-1 consumer + FC head.
// One gate per thread; weights as 64 h2 regs; v_dot2 dots; h via LDS broadcast.
// Handoff batched x4: one flag release (vmcnt drain) per 4 steps; consumer
// prefetches 4 chunks >=5 steps ahead into an 8-deep LDS ring.
// Producer never waits => deadlock-free.
// ---------------------------------------------------------------------------
__global__ __launch_bounds__(512, 2) void fused_rec2(
    const float* __restrict__ xg,     // [B*T][512], layer-0 biases folded
    const float* __restrict__ w_hh0,
    const float* __restrict__ w_ih1,
    const float* __restrict__ w_hh1,
    const float* __restrict__ b_ih1,
    const float* __restrict__ b_hh1,
    const float* __restrict__ fc_w,
    const float* __restrict__ fc_b,
    unsigned int* __restrict__ h1g,   // [128][512][64] h as half2-in-uint
    int* __restrict__ flags,          // [128][64], poisoned negative
    float* __restrict__ logits)       // [128][8]
{
    const int blk = blockIdx.x;
    const bool L1 = blk >= BATCH;
    const int b = blk & (BATCH - 1);
    const int g = threadIdx.x;        // gate 0..511

    __shared__ __align__(16) _Float16 h16[HID];        // h_{t-1} (this layer)
    __shared__ __align__(16) float act_s[GATES];
    __shared__ __align__(16) unsigned int hin[8][64];  // consumer h0 ring
    __shared__ __align__(16) float hfin[HID];

    h2_t whh[64], wih[64];
    {
        const float4* w4 = (const float4*)((L1 ? w_hh1 : w_hh0) + (size_t)g * HID);
        #pragma unroll
        for (int i = 0; i < 32; ++i) {
            float4 v = w4[i];
            whh[2 * i]     = (h2_t){(_Float16)v.x, (_Float16)v.y};
            whh[2 * i + 1] = (h2_t){(_Float16)v.z, (_Float16)v.w};
        }
    }
    float bias = 0.f;
    if (L1) {
        const float4* w4 = (const float4*)(w_ih1 + (size_t)g * HID);
        #pragma unroll
        for (int i = 0; i < 32; ++i) {
            float4 v = w4[i];
            wih[2 * i]     = (h2_t){(_Float16)v.x, (_Float16)v.y};
            wih[2 * i + 1] = (h2_t){(_Float16)v.z, (_Float16)v.w};
        }
        bias = b_ih1[g] + b_hh1[g];
    }

    if (g < HID) h16[g] = (_Float16)0.f;
    float c = 0.f;

    unsigned int* h1row = h1g + (size_t)b * TSTEPS * 64;
    int* flagb = flags + b * 64;

    if (L1 && g < 64) {   // prologue: chunks 0..7 (flag>=8 covers all)
        while (__hip_atomic_load(&flagb[g], __ATOMIC_ACQUIRE, __HIP_MEMORY_SCOPE_AGENT) < 8) {}
        #pragma unroll
        for (int d = 0; d < 8; ++d)
            hin[d][g] = __hip_atomic_load(&h1row[(size_t)d * 64 + g],
                                          __ATOMIC_RELAXED, __HIP_MEMORY_SCOPE_AGENT);
    }

    const float* xgb = xg + (size_t)b * TSTEPS * GATES + g;
    float xcur[4], xnxt[4];
    if (!L1) {
        #pragma unroll
        for (int u = 0; u < 4; ++u) xcur[u] = xgb[(size_t)u * GATES];
    }
    __syncthreads();

    for (int t4 = 0; t4 < 128; ++t4) {
        if (!L1) {   // group-prefetch xg for next 4 steps (coalesced)
            const int tn = (t4 + 1 < 128) ? (t4 + 1) * 4 : t4 * 4;
            #pragma unroll
            for (int u = 0; u < 4; ++u) xnxt[u] = xgb[(size_t)(tn + u) * GATES];
        }
        #pragma unroll
        for (int u = 0; u < 4; ++u) {
            const int t = t4 * 4 + u;
            float p0 = 0.f, p1 = 0.f, p2 = 0.f, p3 = 0.f;
            {
                const half8* hv = (const half8*)h16;
                #pragma unroll
                for (int j = 0; j < 16; ++j) {
                    half8 hh = hv[j];
                    p0 = fdot2h(whh[4 * j],     (h2_t){hh[0], hh[1]}, p0);
                    p1 = fdot2h(whh[4 * j + 1], (h2_t){hh[2], hh[3]}, p1);
                    p2 = fdot2h(whh[4 * j + 2], (h2_t){hh[4], hh[5]}, p2);
                    p3 = fdot2h(whh[4 * j + 3], (h2_t){hh[6], hh[7]}, p3);
                }
            }
            if (L1) {
                const half8* xv8 = (const half8*)&hin[t & 7][0];
                #pragma unroll
                for (int j = 0; j < 16; ++j) {
                    half8 hh = xv8[j];
                    p0 = fdot2h(wih[4 * j],     (h2_t){hh[0], hh[1]}, p0);
                    p1 = fdot2h(wih[4 * j + 1], (h2_t){hh[2], hh[3]}, p1);
                    p2 = fdot2h(wih[4 * j + 2], (h2_t){hh[4], hh[5]}, p2);
                    p3 = fdot2h(wih[4 * j + 3], (h2_t){hh[6], hh[7]}, p3);
                }
            }
            const float s = (p0 + p1) + (p2 + p3) + (L1 ? bias : xcur[u]);
            act_s[g] = ((g >> 7) == 2) ? tanhf_fast(s) : sigmoidf_fast(s);
            __syncthreads();
            if (g < HID) {
                const float ig = act_s[g];
                const float fg = act_s[g + 128];
                const float gg = act_s[g + 256];
                const float og = act_s[g + 384];
                c = __fmaf_rn(fg, c, ig * gg);
                const float h = og * tanhf_fast(c);
                h16[g] = (_Float16)h;
                if (L1 && t == TSTEPS - 1) hfin[g] = h;
            }
            __syncthreads();
            if (!L1 && g < 64) {
                __hip_atomic_store(&h1row[(size_t)t * 64 + g], ((const unsigned int*)h16)[g],
                                   __ATOMIC_RELAXED, __HIP_MEMORY_SCOPE_AGENT);
                if (u == 3)
                    __hip_atomic_store(&flagb[g], t + 1,
                                       __ATOMIC_RELEASE, __HIP_MEMORY_SCOPE_AGENT);
            }
            if (L1 && g < 64 && u == 3) {
                const int tgt = t + 5;            // chunks t+5..t+8
                if (tgt + 3 < TSTEPS) {
                    while (__hip_atomic_load(&flagb[g], __ATOMIC_ACQUIRE,
                                             __HIP_MEMORY_SCOPE_AGENT) < tgt + 4) {}
                    #pragma unroll
                    for (int d = 0; d < 4; ++d)
                        hin[(tgt + d) & 7][g] =
                            __hip_atomic_load(&h1row[(size_t)(tgt + d) * 64 + g],
                                              __ATOMIC_RELAXED, __HIP_MEMORY_SCOPE_AGENT);
                }
            }
        }
        if (!L1) {
            xcur[0] = xnxt[0]; xcur[1] = xnxt[1]; xcur[2] = xnxt[2]; xcur[3] = xnxt[3];
        }
    }

    if (L1) {
        __syncthreads();
        if (g < 8) {
            float s2 = fc_b[g];
            const float* wr = fc_w + g * HID;
            #pragma unroll 4
            for (int k2 = 0; k2 < HID; ++k2) s2 = __fmaf_rn(wr[k2], hfin[k2], s2);
            logits[b * 8 + g] = s2;
        }
    }
}

// ---------------------------------------------------------------------------
extern "C" void kernel_launch(void* const* d_in, const int* in_sizes, int n_in,
                              void* d_out, int out_size, void* d_ws, size_t ws_size,
                              hipStream_t stream) {
    const float* x     = (const float*)d_in[0];
    const float* w_ih0 = (const float*)d_in[1];
    const float* w_hh0 = (const float*)d_in[2];
    const float* b_ih0 = (const float*)d_in[3];
    const float* b_hh0 = (const float*)d_in[4];
    const float* w_ih1 = (const float*)d_in[5];
    const float* w_hh1 = (const float*)d_in[6];
    const float* b_ih1 = (const float*)d_in[7];
    const float* b_hh1 = (const float*)d_in[8];
    const float* fc_w  = (const float*)d_in[9];
    const float* fc_b  = (const float*)d_in[10];
    float* out = (float*)d_out;

    // ws: xg 128MB | Wh 1MB | Wl 1MB | h1g 16MB | flags 32KB  (~146MB)
    char* ws = (char*)d_ws;
    float*        xgb   = (float*)ws;
    _Float16*     Whp   = (_Float16*)(ws + (size_t)M_TOTAL * GATES * 4);
    _Float16*     Wlp   = (_Float16*)(ws + (size_t)M_TOTAL * GATES * 4 + 1048576);
    unsigned int* h1g   = (unsigned int*)(ws + (size_t)M_TOTAL * GATES * 4 + 2097152);
    int*          flags = (int*)(ws + (size_t)M_TOTAL * GATES * 4 + 2097152
                                    + (size_t)BATCH * TSTEPS * 64 * 4);

    convert_w<<<dim3(512), dim3(256), 0, stream>>>(w_ih0, Whp, Wlp);
    gemm_mfma<<<dim3(4, 512), dim3(256), 0, stream>>>(x, Whp, Wlp, b_ih0, b_hh0, xgb);
    fused_rec2<<<dim3(2 * BATCH), dim3(512), 0, stream>>>(
        xgb, w_hh0, w_ih1, w_hh1, b_ih1, b_hh1, fc_w, fc_b, h1g, flags, out);
}